// Round 7
// baseline (177.885 us; speedup 1.0000x reference)
//
#include <hip/hip_runtime.h>

typedef short s16x8 __attribute__((ext_vector_type(8)));
typedef float f32x4 __attribute__((ext_vector_type(4)));
typedef float f32x16 __attribute__((ext_vector_type(16)));

#define B_ 4
#define C_ 256
#define S_ 4096
#define LOG2E 1.44269504088896f
#define M2 32.0f   // fixed base-2 softmax offset: p = 2^(s' - M2)

#if __has_builtin(__builtin_amdgcn_exp2f)
#define EXP2(x) __builtin_amdgcn_exp2f(x)
#else
#define EXP2(x) __exp2f(x)
#endif

// RNE float -> bf16
__device__ __forceinline__ unsigned short f2b(float f) {
  union { float f; unsigned u; } v; v.f = f;
  unsigned r = v.u + 0x7fffu + ((v.u >> 16) & 1u);
  return (unsigned short)(r >> 16);
}
// cheap round-half-up float -> bf16 (hot loop)
__device__ __forceinline__ unsigned short f2b_fast(float f) {
  union { float f; unsigned u; } v; v.f = f;
  return (unsigned short)((v.u + 0x8000u) >> 16);
}
// 16B LDS load at 8B alignment
__device__ __forceinline__ s16x8 lds_ld8(const unsigned short* p) {
  union { s16x8 v; uint2 u[2]; } r;
  r.u[0] = *(const uint2*)p;
  r.u[1] = *(const uint2*)(p + 4);
  return r.v;
}

// ---- weight prep: f32 -> bf16, LOG2E folded into Wq, biases folded ----------
// Wb rows: 0-31 = LOG2E*wq, 32-63 = wk, 64-319 = wv.  bqk: [0..31]=LOG2E*bq,
// [32..63]=bk.  Runs once; removes all per-block weight conversion from proj.
__global__ __launch_bounds__(256)
void prep_kernel(const float* __restrict__ wq, const float* __restrict__ bq,
                 const float* __restrict__ wk, const float* __restrict__ bk,
                 const float* __restrict__ wv,
                 unsigned short* __restrict__ Wb, float* __restrict__ bqk) {
  const int t = threadIdx.x;
  const int r = blockIdx.x * 4 + (t >> 6);
  const int c4 = (t & 63) * 4;
  const float* src; float scale = 1.0f;
  if (r < 32)      { src = wq + (size_t)r * 256;        scale = LOG2E; }
  else if (r < 64) { src = wk + (size_t)(r - 32) * 256; }
  else             { src = wv + (size_t)(r - 64) * 256; }
  f32x4 v = *(const f32x4*)(src + c4);
  union { unsigned short us[4]; uint2 u2; } pk;
  #pragma unroll
  for (int i = 0; i < 4; ++i) pk.us[i] = f2b(v[i] * scale);
  *(uint2*)&Wb[(size_t)r * 256 + c4] = pk.u2;
  if (blockIdx.x == 0 && t < 64) bqk[t] = (t < 32) ? bq[t] * LOG2E : bk[t - 32];
}

// ---- fused QKV projection (MFMA), single source staging ---------------------
// Grid (128, 4): ctype = x>>6 (0: QK from input, 1: all 256 V ch from original),
// jt = x&63, b = y.  Source tile [64n x 256c] staged ONCE into LDS (orig read
// 1x instead of 4x); weight fragments loaded directly from L2-hot bf16 Wb.
// Qb,Kb: [B][S][32] bf16 (n-major).
// Vf: fragment-order tiles: [b][jt][cg][vv][kb][lane64][8] bf16 (8 MB), where
//     element = V[ch = cg*64+vv*32+(lane&31)][j = jt*64 + kb*16 + (lane>>5)*8 + e]
__global__ __launch_bounds__(256)
void proj_kernel(const float* __restrict__ x, const float* __restrict__ orig,
                 const unsigned short* __restrict__ Wb,
                 const float* __restrict__ bqk, const float* __restrict__ bv,
                 unsigned short* __restrict__ Qb, unsigned short* __restrict__ Kb,
                 unsigned short* __restrict__ Vf) {
  __shared__ unsigned short Sl[64 * 260];   // [n][c] bf16, all 256 c (+4 pad)
  __shared__ unsigned short Rl[64 * 68];    // repack buffer
  const int ctype = blockIdx.x >> 6;
  const int jt = blockIdx.x & 63;
  const int n0 = jt * 64;
  const int b  = blockIdx.y;
  const int t  = threadIdx.x;
  const int L = t & 63, w = t >> 6;
  const int mt = w >> 1, nt = w & 1;
  const int g = L >> 5, l32 = L & 31;
  const float* srcb = ((ctype == 0) ? x : orig) + (size_t)b * C_ * S_;

  // stage source transposed Sl[n][c] (64 x 256), vectorized 8B LDS writes
  {
    const int c4 = (t >> 4) * 4;
    const int n4 = (t & 15) * 4;
    #pragma unroll
    for (int kc = 0; kc < 4; ++kc) {
      const int k0 = kc * 64;
      f32x4 v0 = *(const f32x4*)(srcb + (size_t)(k0 + c4 + 0) * S_ + n0 + n4);
      f32x4 v1 = *(const f32x4*)(srcb + (size_t)(k0 + c4 + 1) * S_ + n0 + n4);
      f32x4 v2 = *(const f32x4*)(srcb + (size_t)(k0 + c4 + 2) * S_ + n0 + n4);
      f32x4 v3 = *(const f32x4*)(srcb + (size_t)(k0 + c4 + 3) * S_ + n0 + n4);
      #pragma unroll
      for (int k = 0; k < 4; ++k) {
        union { unsigned short us[4]; uint2 u2; } pk;
        pk.us[0] = f2b(v0[k]); pk.us[1] = f2b(v1[k]);
        pk.us[2] = f2b(v2[k]); pk.us[3] = f2b(v3[k]);
        *(uint2*)&Sl[(n4 + k) * 260 + k0 + c4] = pk.u2;
      }
    }
  }
  __syncthreads();

  const int n = nt * 32 + l32;
  if (ctype == 0) {
    // ---- QK: Wb rows 0..63
    f32x16 acc = (f32x16)0.0f;
    #pragma unroll
    for (int kc = 0; kc < 4; ++kc) {
      #pragma unroll
      for (int ks = 0; ks < 4; ++ks) {
        const s16x8 af = *(const s16x8*)(Wb + (size_t)(mt * 32 + l32) * 256 + kc * 64 + ks * 16 + g * 8);
        const s16x8 bf = lds_ld8(&Sl[(nt * 32 + l32) * 260 + kc * 64 + ks * 16 + g * 8]);
        acc = __builtin_amdgcn_mfma_f32_32x32x16_bf16(af, bf, acc, 0, 0, 0);
      }
    }
    // dump [n][ch]: ch 0..31 = Q (pre-scaled), 32..63 = K
    #pragma unroll
    for (int reg = 0; reg < 16; ++reg) {
      const int rr = (reg & 3) + 8 * (reg >> 2) + 4 * g;
      Rl[n * 68 + mt * 32 + rr] = f2b(acc[reg] + bqk[mt * 32 + rr]);
    }
    __syncthreads();
    const int nn = t >> 2, ch0 = (t & 3) * 16;
    s16x8 a = lds_ld8(Rl + nn * 68 + ch0);
    s16x8 c = lds_ld8(Rl + nn * 68 + ch0 + 8);
    unsigned short* dst = (ch0 < 32)
        ? Qb + ((size_t)b * S_ + n0 + nn) * 32 + ch0
        : Kb + ((size_t)b * S_ + n0 + nn) * 32 + (ch0 - 32);
    *(s16x8*)dst = a;
    *(s16x8*)(dst + 8) = c;
  } else {
    // ---- V: 4 channel groups from the SAME staged source
    #pragma unroll 1
    for (int cg = 0; cg < 4; ++cg) {
      f32x16 acc = (f32x16)0.0f;
      const unsigned short* Wg = Wb + (size_t)(64 + cg * 64 + mt * 32 + l32) * 256;
      #pragma unroll
      for (int kc = 0; kc < 4; ++kc) {
        #pragma unroll
        for (int ks = 0; ks < 4; ++ks) {
          const s16x8 af = *(const s16x8*)(Wg + kc * 64 + ks * 16 + g * 8);
          const s16x8 bf = lds_ld8(&Sl[(nt * 32 + l32) * 260 + kc * 64 + ks * 16 + g * 8]);
          acc = __builtin_amdgcn_mfma_f32_32x32x16_bf16(af, bf, acc, 0, 0, 0);
        }
      }
      // dump [ch][j]
      #pragma unroll
      for (int reg = 0; reg < 16; ++reg) {
        const int rr = (reg & 3) + 8 * (reg >> 2) + 4 * g;
        const int ch = mt * 32 + rr;
        Rl[ch * 68 + n] = f2b(acc[reg] + bv[cg * 64 + ch]);
      }
      __syncthreads();
      unsigned short* grp = Vf + ((size_t)(b * 64 + jt) * 4 + cg) * 4096;
      #pragma unroll
      for (int k = 0; k < 2; ++k) {
        const int G = t * 2 + k;
        const int vv = G >> 8, kb = (G >> 6) & 3, Lf = G & 63;
        const int ch64 = vv * 32 + (Lf & 31);
        const int j64  = kb * 16 + (Lf >> 5) * 8;
        s16x8 v = lds_ld8(Rl + ch64 * 68 + j64);
        *(s16x8*)(grp + G * 8) = v;
      }
      __syncthreads();   // Rl reused next cg
    }
  }
}

// ---- flash attention, fixed-offset base-2 softmax (R1 structure) ------------
// 512 threads (8 waves), i-tile 64, grid 256 (1 block/CU), j-tile 64.
// Phase A: wave (rh,jh): rows rh*16.. x j-half jh*32..; p = exp2(s-M2); P->LDS.
// Phase B: wave (dup,cg): 64 ch (cg) x 64 i, kb-split (dup) -> 4 accs;
//          V fragments via single coalesced global loads (pre-swizzled Vf).
union FlashU {
  unsigned short P[64 * 68];   // 8704 B
  float scr[2][32 * 258];      // 66048 B (epilogue, 2 dup planes x 32 i-rows)
};

__global__ __launch_bounds__(512, 4)
void flash_kernel(const unsigned short* __restrict__ Qb,
                  const unsigned short* __restrict__ Kb,
                  const unsigned short* __restrict__ Vf,
                  const float* __restrict__ inp,
                  const float* __restrict__ gamma,
                  float* __restrict__ out) {
  __shared__ FlashU sm;
  __shared__ float lpart[2][64];
  __shared__ float invl[64];
  const int l  = blockIdx.x;
  const int b  = (l & 7) >> 1;                       // XCD pair per batch
  const int i0 = ((l >> 3) * 2 + (l & 1)) * 64;
  const int t  = threadIdx.x;
  const int L = t & 63, w = t >> 6;
  const int q4 = L >> 4, c16 = L & 15;
  const int g  = L >> 5, l32 = L & 31;
  const int rh = w & 3, jh = w >> 2;                 // phase A role
  const int cg = w & 3, dup = w >> 2;                // phase B role
  const float gam = gamma[0];
  const unsigned short* Kbase = Kb + (size_t)b * S_ * 32;
  const s16x8 qf = *(const s16x8*)(Qb + ((size_t)b * S_ + i0 + rh * 16 + c16) * 32 + q4 * 8);

  f32x16 acc00 = (f32x16)0.0f, acc01 = (f32x16)0.0f;  // i 0..31  x ch {vv0,vv1}
  f32x16 acc10 = (f32x16)0.0f, acc11 = (f32x16)0.0f;  // i 32..63
  float lp[4] = {0.f, 0.f, 0.f, 0.f};

  // preload K frags for j0=0
  s16x8 kc0 = *(const s16x8*)(Kbase + (size_t)(jh * 32 + c16) * 32 + q4 * 8);
  s16x8 kc1 = *(const s16x8*)(Kbase + (size_t)(jh * 32 + 16 + c16) * 32 + q4 * 8);

  for (int j0 = 0; j0 < S_; j0 += 64) {
    const int jt = j0 >> 6;
    // prefetch next-iter K frags (consumed next phase A)
    const int jn = (j0 + 64 < S_) ? j0 + 64 : j0;
    s16x8 kn0 = *(const s16x8*)(Kbase + (size_t)(jn + jh * 32 + c16) * 32 + q4 * 8);
    s16x8 kn1 = *(const s16x8*)(Kbase + (size_t)(jn + jh * 32 + 16 + c16) * 32 + q4 * 8);
    // V fragments: one coalesced 1KB load each (pre-swizzled layout)
    const unsigned short* vbase = Vf + ((size_t)(b * 64 + jt) * 4 + cg) * 4096;
    s16x8 vf00 = *(const s16x8*)(vbase + (dup * 2 + 0) * 512 + L * 8);           // vv=0,kk=0
    s16x8 vf01 = *(const s16x8*)(vbase + 2048 + (dup * 2 + 0) * 512 + L * 8);    // vv=1,kk=0
    s16x8 vf10 = *(const s16x8*)(vbase + (dup * 2 + 1) * 512 + L * 8);           // vv=0,kk=1
    s16x8 vf11 = *(const s16x8*)(vbase + 2048 + (dup * 2 + 1) * 512 + L * 8);    // vv=1,kk=1
    // ---- Phase A
    f32x4 cinit = (f32x4)(-M2);
    f32x4 s0 = __builtin_amdgcn_mfma_f32_16x16x32_bf16(qf, kc0, cinit, 0, 0, 0);
    f32x4 s1 = __builtin_amdgcn_mfma_f32_16x16x32_bf16(qf, kc1, cinit, 0, 0, 0);
    #pragma unroll
    for (int r = 0; r < 4; ++r) {
      const float p0 = EXP2(s0[r]);
      const float p1 = EXP2(s1[r]);
      lp[r] += p0 + p1;
      const int row = rh * 16 + q4 * 4 + r;
      sm.P[row * 68 + jh * 32 + c16]      = f2b_fast(p0);
      sm.P[row * 68 + jh * 32 + 16 + c16] = f2b_fast(p1);
    }
    __syncthreads();   // P visible (also drains vf, needed immediately)
    // ---- Phase B: kb-split (dup), 2x2 register blocking
    {
      const int ko0 = (dup * 2 + 0) * 16 + g * 8;
      const s16x8 pf0 = lds_ld8(sm.P + l32 * 68 + ko0);
      const s16x8 pf1 = lds_ld8(sm.P + (32 + l32) * 68 + ko0);
      acc00 = __builtin_amdgcn_mfma_f32_32x32x16_bf16(pf0, vf00, acc00, 0, 0, 0);
      acc01 = __builtin_amdgcn_mfma_f32_32x32x16_bf16(pf0, vf01, acc01, 0, 0, 0);
      acc10 = __builtin_amdgcn_mfma_f32_32x32x16_bf16(pf1, vf00, acc10, 0, 0, 0);
      acc11 = __builtin_amdgcn_mfma_f32_32x32x16_bf16(pf1, vf01, acc11, 0, 0, 0);
    }
    {
      const int ko1 = (dup * 2 + 1) * 16 + g * 8;
      const s16x8 pf0 = lds_ld8(sm.P + l32 * 68 + ko1);
      const s16x8 pf1 = lds_ld8(sm.P + (32 + l32) * 68 + ko1);
      acc00 = __builtin_amdgcn_mfma_f32_32x32x16_bf16(pf0, vf10, acc00, 0, 0, 0);
      acc01 = __builtin_amdgcn_mfma_f32_32x32x16_bf16(pf0, vf11, acc01, 0, 0, 0);
      acc10 = __builtin_amdgcn_mfma_f32_32x32x16_bf16(pf1, vf10, acc10, 0, 0, 0);
      acc11 = __builtin_amdgcn_mfma_f32_32x32x16_bf16(pf1, vf11, acc11, 0, 0, 0);
    }
    __syncthreads();   // P consumed
    kc0 = kn0; kc1 = kn1;
  }
  // ---- l reduction
  #pragma unroll
  for (int r = 0; r < 4; ++r) {
    float v = lp[r];
    #pragma unroll
    for (int d = 1; d < 16; d <<= 1) v += __shfl_xor(v, d, 64);
    lp[r] = v;
  }
  if (c16 == 0) {
    #pragma unroll
    for (int r = 0; r < 4; ++r) lpart[jh][rh * 16 + q4 * 4 + r] = lp[r];
  }
  __syncthreads();
  if (t < 64) invl[t] = gam / (lpart[0][t] + lpart[1][t]);
  // ---- epilogue: 2 passes over i-halves; dup planes summed at store
  #pragma unroll
  for (int h = 0; h < 2; ++h) {
    const f32x16 a0 = h ? acc10 : acc00;
    const f32x16 a1 = h ? acc11 : acc01;
    float* pl = sm.scr[dup];
    #pragma unroll
    for (int reg = 0; reg < 16; ++reg) {
      const int rr = (reg & 3) + 8 * (reg >> 2) + 4 * g;
      pl[rr * 258 + cg * 64 + l32]      = a0[reg];
      pl[rr * 258 + cg * 64 + 32 + l32] = a1[reg];
    }
    __syncthreads();   // (first pass also publishes invl)
    const int ch = t >> 1;
    const int il16 = (t & 1) * 16;
    #pragma unroll
    for (int q = 0; q < 4; ++q) {
      const int iloc = il16 + q * 4;
      const size_t gi = ((size_t)b * C_ + ch) * S_ + i0 + h * 32 + iloc;
      const f32x4 iv = *(const f32x4*)(inp + gi);
      f32x4 o;
      #pragma unroll
      for (int k = 0; k < 4; ++k) {
        const int il = iloc + k;
        o[k] = (sm.scr[0][il * 258 + ch] + sm.scr[1][il * 258 + ch]) * invl[h * 32 + il] + iv[k];
      }
      *(f32x4*)(out + gi) = o;
    }
    __syncthreads();   // scr free for next pass
  }
}

// ---- launch -----------------------------------------------------------------
extern "C" void kernel_launch(void* const* d_in, const int* in_sizes, int n_in,
                              void* d_out, int out_size, void* d_ws, size_t ws_size,
                              hipStream_t stream) {
  const float* inp   = (const float*)d_in[0];
  const float* orig  = (const float*)d_in[1];
  const float* wq    = (const float*)d_in[2];
  const float* bq    = (const float*)d_in[3];
  const float* wk    = (const float*)d_in[4];
  const float* bk    = (const float*)d_in[5];
  const float* wv    = (const float*)d_in[6];
  const float* bv    = (const float*)d_in[7];
  const float* gamma = (const float*)d_in[8];
  float* out = (float*)d_out;

  unsigned short* Qb = (unsigned short*)d_ws;            // [B][S][32] bf16, 1 MB
  unsigned short* Kb = Qb + (size_t)B_ * S_ * 32;        // [B][S][32] bf16, 1 MB
  unsigned short* Vf = Kb + (size_t)B_ * S_ * 32;        // frag-tiled V, 8 MB
  unsigned short* Wb = Vf + (size_t)B_ * 64 * 4 * 4096;  // bf16 weights, 160 KB
  float* bqk = (float*)(Wb + 320 * 256);                 // folded QK biases

  prep_kernel<<<80, 256, 0, stream>>>(wq, bq, wk, bk, wv, Wb, bqk);
  proj_kernel<<<dim3(128, 4), 256, 0, stream>>>(inp, orig, Wb, bqk, bv, Qb, Kb, Vf);
  flash_kernel<<<256, 512, 0, stream>>>(Qb, Kb, Vf, inp, gamma, out);
}

// Round 8
// 157.969 us; speedup vs baseline: 1.1261x; 1.1261x over previous
//
#include <hip/hip_runtime.h>

typedef short s16x8 __attribute__((ext_vector_type(8)));
typedef float f32x4 __attribute__((ext_vector_type(4)));
typedef float f32x16 __attribute__((ext_vector_type(16)));

#define B_ 4
#define C_ 256
#define S_ 4096
#define LOG2E 1.44269504088896f
#define M2 32.0f   // fixed base-2 softmax offset: p = 2^(s' - M2)

#if __has_builtin(__builtin_amdgcn_exp2f)
#define EXP2(x) __builtin_amdgcn_exp2f(x)
#else
#define EXP2(x) __exp2f(x)
#endif

// RNE float -> bf16
__device__ __forceinline__ unsigned short f2b(float f) {
  union { float f; unsigned u; } v; v.f = f;
  unsigned r = v.u + 0x7fffu + ((v.u >> 16) & 1u);
  return (unsigned short)(r >> 16);
}
// cheap round-half-up float -> bf16 (hot loop)
__device__ __forceinline__ unsigned short f2b_fast(float f) {
  union { float f; unsigned u; } v; v.f = f;
  return (unsigned short)((v.u + 0x8000u) >> 16);
}
#define PK2(x, y) ((unsigned)f2b_fast(x) | ((unsigned)f2b_fast(y) << 16))
// 16B LDS load at 8B alignment
__device__ __forceinline__ s16x8 lds_ld8(const unsigned short* p) {
  union { s16x8 v; uint2 u[2]; } r;
  r.u[0] = *(const uint2*)p;
  r.u[1] = *(const uint2*)(p + 4);
  return r.v;
}

// ---- fused QKV projection (MFMA) --------------------------------------------
// ct==0:  rows 0-31 = Q (scaled by LOG2E), rows 32-63 = K (from input)
// ct 1-4: rows = Wv[(ct-1)*64 .. +64) (from original)
// Qb,Kb: [B][S][32] bf16 (n-major).
// Vf (v2, PERMUTED frag layout): [b][jt32(128)][g(8)][s(2)][lane64][e8] bf16,
//   element = V[ch = g*32+(l&31)][ jt32*32 + s*16 + (e&3) + (e>>2)*8 + (l>>5)*4 ]
//   The j-permutation matches the in-register P A-frag order in flash (see below).
__global__ __launch_bounds__(256)
void proj_kernel(const float* __restrict__ x, const float* __restrict__ orig,
                 const float* __restrict__ wq, const float* __restrict__ bq,
                 const float* __restrict__ wk, const float* __restrict__ bk,
                 const float* __restrict__ wv, const float* __restrict__ bv,
                 unsigned short* __restrict__ Qb, unsigned short* __restrict__ Kb,
                 unsigned short* __restrict__ Vf) {
  __shared__ unsigned short Al[64 * 68];
  __shared__ unsigned short Sl[64 * 68];
  const int ct = blockIdx.x >> 6;
  const int jt = blockIdx.x & 63;
  const int n0 = jt * 64;
  const int b  = blockIdx.y;
  const int t  = threadIdx.x;
  const int L = t & 63, w = t >> 6;
  const int mt = w >> 1, nt = w & 1;
  const int g = L >> 5, l32 = L & 31;
  const float* srcb = ((ct == 0) ? x : orig) + (size_t)b * C_ * S_;
  f32x16 acc = (f32x16)0.0f;

  for (int kc = 0; kc < 4; ++kc) {
    const int k0 = kc * 64;
    __syncthreads();
    // stage weights Al[row][c] (64x64)
    #pragma unroll
    for (int rep = 0; rep < 4; ++rep) {
      const int idx = rep * 256 + t;
      const int row = idx >> 4, c4 = (idx & 15) * 4;
      const float* wsrc; int wrow;
      if (ct == 0) {
        if (row < 32) { wsrc = wq; wrow = row; } else { wsrc = wk; wrow = row - 32; }
      } else { wsrc = wv; wrow = (ct - 1) * 64 + row; }
      f32x4 v = *(const f32x4*)(wsrc + (size_t)wrow * 256 + k0 + c4);
      union { unsigned short us[4]; uint2 u2; } pk;
      #pragma unroll
      for (int i = 0; i < 4; ++i) pk.us[i] = f2b(v[i]);
      *(uint2*)&Al[row * 68 + c4] = pk.u2;
    }
    // stage source transposed Sl[n][c], vectorized 8B LDS writes
    {
      const int c4 = (t >> 4) * 4;
      const int n4 = (t & 15) * 4;
      f32x4 v0 = *(const f32x4*)(srcb + (size_t)(k0 + c4 + 0) * S_ + n0 + n4);
      f32x4 v1 = *(const f32x4*)(srcb + (size_t)(k0 + c4 + 1) * S_ + n0 + n4);
      f32x4 v2 = *(const f32x4*)(srcb + (size_t)(k0 + c4 + 2) * S_ + n0 + n4);
      f32x4 v3 = *(const f32x4*)(srcb + (size_t)(k0 + c4 + 3) * S_ + n0 + n4);
      #pragma unroll
      for (int k = 0; k < 4; ++k) {
        union { unsigned short us[4]; uint2 u2; } pk;
        pk.us[0] = f2b(v0[k]); pk.us[1] = f2b(v1[k]);
        pk.us[2] = f2b(v2[k]); pk.us[3] = f2b(v3[k]);
        *(uint2*)&Sl[(n4 + k) * 68 + c4] = pk.u2;
      }
    }
    __syncthreads();
    #pragma unroll
    for (int ks = 0; ks < 4; ++ks) {
      s16x8 af = lds_ld8(&Al[(mt * 32 + l32) * 68 + ks * 16 + g * 8]);
      s16x8 bf = lds_ld8(&Sl[(nt * 32 + l32) * 68 + ks * 16 + g * 8]);
      acc = __builtin_amdgcn_mfma_f32_32x32x16_bf16(af, bf, acc, 0, 0, 0);
    }
  }
  __syncthreads();   // LDS free; reuse Al as repack buffer
  unsigned short* Rl = Al;
  const int n = nt * 32 + l32;
  if (ct == 0) {
    // dump [n][ch]: ch 0..31 = Q, 32..63 = K
    #pragma unroll
    for (int reg = 0; reg < 16; ++reg) {
      const int rr = (reg & 3) + 8 * (reg >> 2) + 4 * g;
      const float val = (mt == 0) ? (acc[reg] + bq[rr]) * LOG2E : acc[reg] + bk[rr];
      Rl[n * 68 + mt * 32 + rr] = f2b(val);
    }
    __syncthreads();
    const int nn = t >> 2, ch0 = (t & 3) * 16;
    s16x8 a = lds_ld8(Rl + nn * 68 + ch0);
    s16x8 c = lds_ld8(Rl + nn * 68 + ch0 + 8);
    unsigned short* dst = (ch0 < 32)
        ? Qb + ((size_t)b * S_ + n0 + nn) * 32 + ch0
        : Kb + ((size_t)b * S_ + n0 + nn) * 32 + (ch0 - 32);
    *(s16x8*)dst = a;
    *(s16x8*)(dst + 8) = c;
  } else {
    const int cg = ct - 1;
    // dump [ch][j]
    #pragma unroll
    for (int reg = 0; reg < 16; ++reg) {
      const int rr = (reg & 3) + 8 * (reg >> 2) + 4 * g;
      const int ch = mt * 32 + rr;
      Rl[ch * 68 + n] = f2b(acc[reg] + bv[cg * 64 + ch]);
    }
    __syncthreads();
    // scatter into Vf2 permuted-frag layout
    #pragma unroll
    for (int k = 0; k < 2; ++k) {
      const int G = t * 2 + k;            // 512 stores of 8 shorts
      const int t2 = G >> 8;              // which jt32 sub-tile of this jt64
      const int gh = (G >> 7) & 1;        // 32-ch half within cg's 64
      const int s  = (G >> 6) & 1;        // 16-j slice within jt32
      const int Lf = G & 63;
      const int hh = Lf >> 5;
      const int ch_l = gh * 32 + (Lf & 31);
      const int jloc = t2 * 32 + s * 16 + hh * 4;
      uint2 q0 = *(const uint2*)&Rl[ch_l * 68 + jloc];       // j: +0..3
      uint2 q1 = *(const uint2*)&Rl[ch_l * 68 + jloc + 8];   // j: +8..11
      unsigned short* dst = Vf + (((size_t)(b * 128 + jt * 2 + t2) * 8)
                                  + cg * 2 + gh) * 1024 + s * 512 + (size_t)Lf * 8;
      *(uint2*)dst = q0;
      *(uint2*)(dst + 4) = q1;
    }
  }
}

// ---- flash attention v3: barrier-free streaming, in-register P --------------
// Grid 256 (b, i0), 512 thr, 8 waves = jq(4) x chh(2); 1 block/CU, 2 waves/SIMD.
// Each wave: 64 i (ig loop), 128 ch (4 cg accs), 1024 j (32 steps of 32j).
// Per step: QK = 2 chained mfma(K,Q) -> lane holds P[i=l&31][16 j on regs];
// exp2 + pack STRAIGHT into PV A-frags (the j-permutation is baked into Vf2);
// 16 PV mfma into 8 persistent accs. NO LDS, NO barriers in the loop.
// V-frags reused across both ig -> 2 MB V-traffic/block (L2-resident per batch).

#define MFMA32(A, B, C) __builtin_amdgcn_mfma_f32_32x32x16_bf16(A, B, C, 0, 0, 0)

#define LOADV(JT)                                                               \
  {                                                                             \
    const unsigned short* vb = Vf + (((size_t)(b * 128 + (JT)) * 8)             \
                                     + chh * 4) * 1024 + (size_t)L * 8;         \
    v00 = *(const s16x8*)(vb + 0 * 1024);                                       \
    v01 = *(const s16x8*)(vb + 0 * 1024 + 512);                                 \
    v10 = *(const s16x8*)(vb + 1 * 1024);                                       \
    v11 = *(const s16x8*)(vb + 1 * 1024 + 512);                                 \
    v20 = *(const s16x8*)(vb + 2 * 1024);                                       \
    v21 = *(const s16x8*)(vb + 2 * 1024 + 512);                                 \
    v30 = *(const s16x8*)(vb + 3 * 1024);                                       \
    v31 = *(const s16x8*)(vb + 3 * 1024 + 512);                                 \
  }

#define DO_IG(QF0, QF1, A0, A1, A2, A3, LPV)                                    \
  {                                                                             \
    f32x16 p = MFMA32(kc0, QF0, cinit);                                         \
    p = MFMA32(kc1, QF1, p);                                                    \
    const float e0 = EXP2(p[0]),  e1 = EXP2(p[1]),  e2 = EXP2(p[2]),  e3 = EXP2(p[3]);   \
    const float e4 = EXP2(p[4]),  e5 = EXP2(p[5]),  e6 = EXP2(p[6]),  e7 = EXP2(p[7]);   \
    const float e8 = EXP2(p[8]),  e9 = EXP2(p[9]),  e10 = EXP2(p[10]), e11 = EXP2(p[11]); \
    const float e12 = EXP2(p[12]), e13 = EXP2(p[13]), e14 = EXP2(p[14]), e15 = EXP2(p[15]); \
    LPV += (((e0 + e1) + (e2 + e3)) + ((e4 + e5) + (e6 + e7)))                  \
         + (((e8 + e9) + (e10 + e11)) + ((e12 + e13) + (e14 + e15)));           \
    union { unsigned u[4]; s16x8 v; } pa, pb;                                   \
    pa.u[0] = PK2(e0, e1);   pa.u[1] = PK2(e2, e3);                             \
    pa.u[2] = PK2(e4, e5);   pa.u[3] = PK2(e6, e7);                             \
    pb.u[0] = PK2(e8, e9);   pb.u[1] = PK2(e10, e11);                           \
    pb.u[2] = PK2(e12, e13); pb.u[3] = PK2(e14, e15);                           \
    A0 = MFMA32(pa.v, v00, A0);  A0 = MFMA32(pb.v, v01, A0);                    \
    A1 = MFMA32(pa.v, v10, A1);  A1 = MFMA32(pb.v, v11, A1);                    \
    A2 = MFMA32(pa.v, v20, A2);  A2 = MFMA32(pb.v, v21, A2);                    \
    A3 = MFMA32(pa.v, v30, A3);  A3 = MFMA32(pb.v, v31, A3);                    \
  }

#define DUMP_ADD(ACC, IG, CG)                                                   \
  _Pragma("unroll")                                                             \
  for (int r = 0; r < 16; ++r) {                                                \
    const int rr = (r & 3) + 8 * (r >> 2) + 4 * h;                              \
    scr[(IG) * 32 + rr][chh * 128 + (CG) * 32 + l31] += ACC[r];                 \
  }

__global__ __launch_bounds__(512, 2)
void flash_kernel(const unsigned short* __restrict__ Qb,
                  const unsigned short* __restrict__ Kb,
                  const unsigned short* __restrict__ Vf,
                  const float* __restrict__ inp,
                  const float* __restrict__ gamma,
                  float* __restrict__ out) {
  __shared__ float scr[64][260];
  __shared__ float lpart[4][64];
  __shared__ float invl[64];
  const int l  = blockIdx.x;
  const int b  = (l & 7) >> 1;                       // XCD pair per batch
  const int i0 = ((l >> 3) * 2 + (l & 1)) * 64;
  const int t  = threadIdx.x;
  const int L = t & 63, w = t >> 6;
  const int l31 = L & 31, h = L >> 5;
  const int jq = w >> 1, chh = w & 1;
  const float gam = gamma[0];
  const unsigned short* Kbase = Kb + (size_t)b * S_ * 32;

  // zero the reduction scratch (consumed after the loop; ph-0 barrier orders it)
  {
    float* sf = &scr[0][0];
    for (int z = t; z < 64 * 260; z += 512) sf[z] = 0.0f;
  }

  // Q fragments (resident): qf[ig][slice]
  const s16x8 qf00 = *(const s16x8*)(Qb + ((size_t)b * S_ + i0 + l31) * 32 + h * 8);
  const s16x8 qf01 = *(const s16x8*)(Qb + ((size_t)b * S_ + i0 + l31) * 32 + 16 + h * 8);
  const s16x8 qf10 = *(const s16x8*)(Qb + ((size_t)b * S_ + i0 + 32 + l31) * 32 + h * 8);
  const s16x8 qf11 = *(const s16x8*)(Qb + ((size_t)b * S_ + i0 + 32 + l31) * 32 + 16 + h * 8);

  f32x16 a00 = (f32x16)0.0f, a01 = (f32x16)0.0f, a02 = (f32x16)0.0f, a03 = (f32x16)0.0f;
  f32x16 a10 = (f32x16)0.0f, a11 = (f32x16)0.0f, a12 = (f32x16)0.0f, a13 = (f32x16)0.0f;
  float lp0 = 0.f, lp1 = 0.f;
  const f32x16 cinit = (f32x16)(-M2);

  s16x8 kc0, kc1, kn0, kn1;
  s16x8 v00, v01, v10, v11, v20, v21, v30, v31;
  {
    const int jt0 = jq * 32;
    kc0 = *(const s16x8*)(Kbase + (size_t)(jt0 * 32 + l31) * 32 + h * 8);
    kc1 = *(const s16x8*)(Kbase + (size_t)(jt0 * 32 + l31) * 32 + 16 + h * 8);
  }

  for (int st = 0; st < 32; ++st) {
    const int jt = jq * 32 + st;
    LOADV(jt);                                   // issued early, consumed ~20 insts later
    DO_IG(qf00, qf01, a00, a01, a02, a03, lp0);  // ig 0
    {
      const int jn = (jt + 1 < 128) ? jt + 1 : 127;   // clamped tail prefetch
      kn0 = *(const s16x8*)(Kbase + (size_t)(jn * 32 + l31) * 32 + h * 8);
      kn1 = *(const s16x8*)(Kbase + (size_t)(jn * 32 + l31) * 32 + 16 + h * 8);
    }
    DO_IG(qf10, qf11, a10, a11, a12, a13, lp1);  // ig 1 (reuses kc, V)
    kc0 = kn0; kc1 = kn1;
  }

  // ---- row-sum partials: lane holds partial for i = ig*32 + l31
  lp0 += __shfl_xor(lp0, 32, 64);
  lp1 += __shfl_xor(lp1, 32, 64);
  if (chh == 0 && L < 32) {
    lpart[jq][L] = lp0;
    lpart[jq][32 + L] = lp1;
  }
  // ---- O reduction over jq via 4 phases (disjoint ch per chh)
  #pragma unroll 1
  for (int ph = 0; ph < 4; ++ph) {
    __syncthreads();
    if (jq == ph) {
      DUMP_ADD(a00, 0, 0); DUMP_ADD(a01, 0, 1); DUMP_ADD(a02, 0, 2); DUMP_ADD(a03, 0, 3);
      DUMP_ADD(a10, 1, 0); DUMP_ADD(a11, 1, 1); DUMP_ADD(a12, 1, 2); DUMP_ADD(a13, 1, 3);
    }
  }
  __syncthreads();
  if (t < 64) invl[t] = gam / (lpart[0][t] + lpart[1][t] + lpart[2][t] + lpart[3][t]);
  __syncthreads();
  // ---- fused store: thread t -> ch = t>>1, i-half = (t&1)*32
  {
    const int ch = t >> 1;
    const int ih = (t & 1) * 32;
    #pragma unroll
    for (int q = 0; q < 8; ++q) {
      const int il = ih + q * 4;
      const size_t gi = ((size_t)b * C_ + ch) * S_ + i0 + il;
      const f32x4 iv = *(const f32x4*)(inp + gi);
      f32x4 o;
      #pragma unroll
      for (int k = 0; k < 4; ++k)
        o[k] = scr[il + k][ch] * invl[il + k] + iv[k];
      *(f32x4*)(out + gi) = o;
    }
  }
}

// ---- launch -----------------------------------------------------------------
extern "C" void kernel_launch(void* const* d_in, const int* in_sizes, int n_in,
                              void* d_out, int out_size, void* d_ws, size_t ws_size,
                              hipStream_t stream) {
  const float* inp   = (const float*)d_in[0];
  const float* orig  = (const float*)d_in[1];
  const float* wq    = (const float*)d_in[2];
  const float* bq    = (const float*)d_in[3];
  const float* wk    = (const float*)d_in[4];
  const float* bk    = (const float*)d_in[5];
  const float* wv    = (const float*)d_in[6];
  const float* bv    = (const float*)d_in[7];
  const float* gamma = (const float*)d_in[8];
  float* out = (float*)d_out;

  unsigned short* Qb = (unsigned short*)d_ws;            // [B][S][32] bf16, 1 MB
  unsigned short* Kb = Qb + (size_t)B_ * S_ * 32;        // [B][S][32] bf16, 1 MB
  unsigned short* Vf = Kb + (size_t)B_ * S_ * 32;        // frag-tiled V (v2), 8 MB

  proj_kernel<<<dim3(320, 4), 256, 0, stream>>>(inp, orig, wq, bq, wk, bk, wv, bv, Qb, Kb, Vf);
  flash_kernel<<<256, 512, 0, stream>>>(Qb, Kb, Vf, inp, gamma, out);
}